// Round 12
// baseline (230.592 us; speedup 1.0000x reference)
//
#include <hip/hip_runtime.h>
#include <hip/hip_bf16.h>

// CrossAttention  B=2, S=2048, D=1024, H=16, HD=64
// R22: R21 probe confirmed the pow2 residency quantum (164 regs -> still
// 2 waves/SIMD; only <=128 TOTAL unlocks 4). R19 (m-half: o32acc+qf16) and
// R20 (c-outer: kfc16+vfc16) each fixed half the pressure; R22 combines
// both: o[4][2]=32acc + qf16 + kfc16 + vfc16 + temps ~115 <= 128 with
// margin. exp in-place into s0/s1 (kills p0/p1, -8 regs) and
// __builtin_amdgcn_exp2f (1 inst vs ocml's ~5). 8-wave blocks (512 thr),
// wave = (key-rank kw, m-half mh); uniform pair (31-p, p); 512 blocks =
// 2/CU = 16 waves/CU = 4 waves/SIMD. K/V L2 read 2x (~15 TB/s agg, under
// ceiling, XCD-local). Combine = R19's per-half tree (correctness-proven).
// prep/qkv/out kernels unchanged.

#define BDIM 2
#define SDIM 2048
#define DDIM 1024
#define HDIM 16
#define HD   64
#define MDIM (BDIM*SDIM)   // 4096
// folded into Q at projection: (1/8) * log2(e)
#define C2 0.18033688011112042f

using short8  = __attribute__((ext_vector_type(8))) short;
using floatx4 = __attribute__((ext_vector_type(4))) float;

static __device__ __forceinline__ unsigned short f2bf(float x) {
    union { float f; unsigned int u; } c; c.f = x;
    unsigned int r = (c.u + 0x7fffu + ((c.u >> 16) & 1u)) >> 16;
    return (unsigned short)r;
}

// pack two fp32 -> (bf16(b)<<16)|bf16(a), round-half-up
static __device__ __forceinline__ unsigned int pack2bf(float a, float b) {
    union { float f; unsigned int u; } ua, ub;
    ua.f = a; ub.f = b;
    return __builtin_amdgcn_perm(ub.u + 0x8000u, ua.u + 0x8000u, 0x07060302u);
}

#define GLD16(g, l) __builtin_amdgcn_global_load_lds(                        \
    (const __attribute__((address_space(1))) void*)(g),                      \
    (__attribute__((address_space(3))) void*)(l), 16, 0, 0)

// ---------------- fused prep: cast x/y -> bf16 (z=0,1), wtrans (z=2) ----------------
__global__ __launch_bounds__(256) void prep_kernel(
    const float* __restrict__ X, const float* __restrict__ Y,
    const float* __restrict__ W0, const float* __restrict__ W1,
    const float* __restrict__ W2, const float* __restrict__ W3,
    unsigned short* __restrict__ Xo, unsigned short* __restrict__ Yo,
    unsigned short* __restrict__ T0, unsigned short* __restrict__ T1,
    unsigned short* __restrict__ T2, unsigned short* __restrict__ T3)
{
    __shared__ float tile[64][68];
    const int z = blockIdx.z;
    const int t = threadIdx.x;
    if (z < 2) {
        const float* A    = z ? Y : X;
        unsigned short* O = z ? Yo : Xo;
        const int idx = blockIdx.x * 256 + t;
        const float4 a = ((const float4*)A)[idx*2];
        const float4 b = ((const float4*)A)[idx*2 + 1];
        ushort4 lo, hi;
        lo.x = f2bf(a.x); lo.y = f2bf(a.y); lo.z = f2bf(a.z); lo.w = f2bf(a.w);
        hi.x = f2bf(b.x); hi.y = f2bf(b.y); hi.z = f2bf(b.z); hi.w = f2bf(b.w);
        ((ushort4*)O)[idx*2]     = lo;
        ((ushort4*)O)[idx*2 + 1] = hi;
        return;
    }
    // z == 2: all four weight transposes, 256 tile-blocks each
    if (blockIdx.x >= 1024) return;
    const int zz = blockIdx.x >> 8;
    const int tx = blockIdx.x & 255;
    const float* W    = (zz == 0) ? W0 : (zz == 1) ? W1 : (zz == 2) ? W2 : W3;
    unsigned short* T = (zz == 0) ? T0 : (zz == 1) ? T1 : (zz == 2) ? T2 : T3;
    const int k0 = (tx & 15) * 64, n0 = (tx >> 4) * 64;
    #pragma unroll
    for (int i = 0; i < 4; ++i) {
        const int idx = t + i*256;
        const int kr = idx >> 4, c4 = idx & 15;
        float4 v = *(const float4*)&W[(size_t)(k0 + kr) * DDIM + n0 + c4*4];
        tile[kr][c4*4+0] = v.x; tile[kr][c4*4+1] = v.y;
        tile[kr][c4*4+2] = v.z; tile[kr][c4*4+3] = v.w;
    }
    __syncthreads();
    #pragma unroll
    for (int i = 0; i < 4; ++i) {
        const int idx = t + i*256;
        const int nr = idx >> 4, kc = idx & 15;
        ushort4 o;
        o.x = f2bf(tile[kc*4+0][nr]); o.y = f2bf(tile[kc*4+1][nr]);
        o.z = f2bf(tile[kc*4+2][nr]); o.w = f2bf(tile[kc*4+3][nr]);
        *(ushort4*)&T[(size_t)(n0 + nr) * DDIM + k0 + kc*4] = o;
    }
}

// ---------------- 128x128 bf16 MFMA GEMM core, LDS double-buffered ----------------
template <bool SWAP>
__device__ __forceinline__ void gemm128_core(
    const unsigned short* __restrict__ A, const unsigned short* __restrict__ Bt,
    int bm, int bn, unsigned short* As, unsigned short* Bs, floatx4 acc[4][4])
{
    const int t = threadIdx.x;
    const int w = t >> 6, l = t & 63;
    const int quad = l >> 4, col = l & 15;
    const int wr = (w >> 1) * 64, wc = (w & 1) * 64;

    const int c1 = t + 256;
    const int r0 = t >> 2,  o0 = (t & 3) * 8;
    const int r1 = c1 >> 2, o1 = (c1 & 3) * 8;

    const unsigned short* Ar0 = A  + (size_t)(bm + r0) * DDIM + o0;
    const unsigned short* Ar1 = A  + (size_t)(bm + r1) * DDIM + o1;
    const unsigned short* Br0 = Bt + (size_t)(bn + r0) * DDIM + o0;
    const unsigned short* Br1 = Bt + (size_t)(bn + r1) * DDIM + o1;

    GLD16(Ar0, As + t*8);
    GLD16(Ar1, As + c1*8);
    GLD16(Br0, Bs + t*8);
    GLD16(Br1, Bs + c1*8);

    for (int kt = 0; kt < DDIM; kt += 32) {
        const int cur = (kt >> 5) & 1;
        unsigned short* Asn = As + (cur ^ 1) * 4096;
        unsigned short* Bsn = Bs + (cur ^ 1) * 4096;
        __syncthreads();
        if (kt + 32 < DDIM) {
            GLD16(Ar0 + kt + 32, Asn + t*8);
            GLD16(Ar1 + kt + 32, Asn + c1*8);
            GLD16(Br0 + kt + 32, Bsn + t*8);
            GLD16(Br1 + kt + 32, Bsn + c1*8);
        }
        const unsigned short* Asc = As + cur*4096;
        const unsigned short* Bsc = Bs + cur*4096;
        short8 af[4], bfr[4];
        #pragma unroll
        for (int i = 0; i < 4; ++i)
            af[i] = *(const short8*)&Asc[(wr + i*16 + col)*32 + quad*8];
        #pragma unroll
        for (int j = 0; j < 4; ++j)
            bfr[j] = *(const short8*)&Bsc[(wc + j*16 + col)*32 + quad*8];
        #pragma unroll
        for (int i = 0; i < 4; ++i)
            #pragma unroll
            for (int j = 0; j < 4; ++j)
                acc[i][j] = SWAP
                    ? __builtin_amdgcn_mfma_f32_16x16x32_bf16(bfr[j], af[i], acc[i][j], 0, 0, 0)
                    : __builtin_amdgcn_mfma_f32_16x16x32_bf16(af[i], bfr[j], acc[i][j], 0, 0, 0);
    }
}

// ---------------- fused Q/K/V projection (grid.z = 0/1/2) ----------------
// XCD swizzle: raw (x,y) with x in [0,8): xcd = x (lin%8). bm = x*4+(y&3),
// bn = y>>2 -> per-XCD A set = 4 tiles (1MB), W = 2MB: both L2-resident.
__global__ __launch_bounds__(256) void qkv_gemm_kernel(
    const unsigned short* __restrict__ xbf, const unsigned short* __restrict__ ybf,
    const unsigned short* __restrict__ Wqt, const unsigned short* __restrict__ Wkt,
    const unsigned short* __restrict__ Wvt,
    const float* __restrict__ bq, const float* __restrict__ bk,
    const float* __restrict__ bv,
    unsigned short* __restrict__ Qbf, unsigned short* __restrict__ Kbf,
    unsigned short* __restrict__ vT)
{
    __shared__ __align__(16) unsigned short As[2*4096];   // 16 KB
    __shared__ __align__(16) unsigned short Bs[2*4096];   // 16 KB

    const int z = blockIdx.z;
    const unsigned short* A  = (z == 0) ? xbf : ybf;
    const unsigned short* Wt = (z == 0) ? Wqt : (z == 1) ? Wkt : Wvt;
    const float* bp          = (z == 0) ? bq  : (z == 1) ? bk  : bv;

    // XCD-aware remap (grid (8,32,z)): xcd = blockIdx.x
    const int bm = (blockIdx.x * 4 + (blockIdx.y & 3)) * 128;
    const int bn = (blockIdx.y >> 2) * 128;

    const int t = threadIdx.x;
    const int w = t >> 6, l = t & 63;
    const int quad = l >> 4, col = l & 15;
    const int wr = (w >> 1) * 64, wc = (w & 1) * 64;

    floatx4 acc[4][4] = {};

    if (z < 2) {
        gemm128_core<true>(A, Wt, bm, bn, As, Bs, acc);
        unsigned short* O = (z == 0) ? Qbf : Kbf;
        const float sc = (z == 0) ? C2 : 1.0f;
        float4 bias4[4];
        #pragma unroll
        for (int j = 0; j < 4; ++j)
            bias4[j] = *(const float4*)&bp[bn + wc + j*16 + quad*4];
        #pragma unroll
        for (int i = 0; i < 4; ++i) {
            const int m = bm + wr + i*16 + col;
            unsigned short* rowp = O + (size_t)m * DDIM;
            #pragma unroll
            for (int j = 0; j < 4; ++j) {
                const float v0 = (acc[i][j][0] + bias4[j].x) * sc;
                const float v1 = (acc[i][j][1] + bias4[j].y) * sc;
                const float v2 = (acc[i][j][2] + bias4[j].z) * sc;
                const float v3 = (acc[i][j][3] + bias4[j].w) * sc;
                uint2 pk;
                pk.x = pack2bf(v0, v1);
                pk.y = pack2bf(v2, v3);
                *(uint2*)&rowp[bn + wc + j*16 + quad*4] = pk;
            }
        }
    } else {
        gemm128_core<false>(A, Wt, bm, bn, As, Bs, acc);
        #pragma unroll
        for (int j = 0; j < 4; ++j) {
            const int gn = bn + wc + j*16 + col;
            const float bias = bp[gn];
            #pragma unroll
            for (int i = 0; i < 4; ++i) {
                const int gm0 = bm + wr + i*16 + quad*4;
                uint2 pk;
                pk.x = pack2bf(acc[i][j][0] + bias, acc[i][j][1] + bias);
                pk.y = pack2bf(acc[i][j][2] + bias, acc[i][j][3] + bias);
                *(uint2*)&vT[((size_t)((gm0 >> 11) * DDIM + gn)) * SDIM + (gm0 & 2047)] = pk;
            }
        }
    }
}

// ---------------- output projection: 128x64 tiles, double-buffered ----------------
// XCD swizzle: grid (16,32); xcd = x&7, j = (x>>3) + 2y in [0,64):
// bm = (x&7)*4 + (j&3), bn = j>>2 -> per-XCD 1MB A + 2MB W, L2-resident.
__global__ __launch_bounds__(256) void out_gemm_kernel(
    const unsigned short* __restrict__ Obf, const unsigned short* __restrict__ Wot,
    const float* __restrict__ bo, float* __restrict__ out)
{
    __shared__ __align__(16) unsigned short As[2*4096];   // 16 KB
    __shared__ __align__(16) unsigned short Bs[2*2048];   // 8 KB

    const int t = threadIdx.x;
    const int w = t >> 6, l = t & 63;
    const int quad = l >> 4, col = l & 15;

    const int j  = (blockIdx.x >> 3) + 2 * blockIdx.y;
    const int bm = ((blockIdx.x & 7) * 4 + (j & 3)) * 128;
    const int bn = (j >> 2) * 64;

    const int wr = (w >> 1) * 64, wc = (w & 1) * 32;

    const int r0 = t >> 2, o0 = (t & 3) * 8;
    const unsigned short* Ar0 = Obf + (size_t)(bm + r0) * DDIM + o0;
    const unsigned short* Ar1 = Obf + (size_t)(bm + 64 + r0) * DDIM + o0;
    const unsigned short* Br  = Wot + (size_t)(bn + r0) * DDIM + o0;

    floatx4 acc[4][2] = {};

    GLD16(Ar0, As + t*8);
    GLD16(Ar1, As + (t + 256)*8);
    GLD16(Br,  Bs + t*8);

    for (int kt = 0; kt < DDIM; kt += 32) {
        const int cur = (kt >> 5) & 1;
        unsigned short* Asn = As + (cur ^ 1) * 4096;
        unsigned short* Bsn = Bs + (cur ^ 1) * 2048;
        __syncthreads();
        if (kt + 32 < DDIM) {
            GLD16(Ar0 + kt + 32, Asn + t*8);
            GLD16(Ar1 + kt + 32, Asn + (t + 256)*8);
            GLD16(Br  + kt + 32, Bsn + t*8);
        }
        const unsigned short* Asc = As + cur*4096;
        const unsigned short* Bsc = Bs + cur*2048;
        short8 af[4], bfr[2];
        #pragma unroll
        for (int i = 0; i < 4; ++i)
            af[i] = *(const short8*)&Asc[(wr + i*16 + col)*32 + quad*8];
        #pragma unroll
        for (int j2 = 0; j2 < 2; ++j2)
            bfr[j2] = *(const short8*)&Bsc[(wc + j2*16 + col)*32 + quad*8];
        #pragma unroll
        for (int i = 0; i < 4; ++i)
            #pragma unroll
            for (int j2 = 0; j2 < 2; ++j2)
                acc[i][j2] = __builtin_amdgcn_mfma_f32_16x16x32_bf16(
                    bfr[j2], af[i], acc[i][j2], 0, 0, 0);
    }

    float4 bias4[2];
    #pragma unroll
    for (int j2 = 0; j2 < 2; ++j2)
        bias4[j2] = *(const float4*)&bo[bn + wc + j2*16 + quad*4];
    #pragma unroll
    for (int i = 0; i < 4; ++i) {
        const int m = bm + wr + i*16 + col;
        float* rowp = out + (size_t)m * DDIM;
        #pragma unroll
        for (int j2 = 0; j2 < 2; ++j2) {
            float4 o;
            o.x = acc[i][j2][0] + bias4[j2].x;
            o.y = acc[i][j2][1] + bias4[j2].y;
            o.z = acc[i][j2][2] + bias4[j2].z;
            o.w = acc[i][j2][3] + bias4[j2].w;
            *(float4*)&rowp[bn + wc + j2*16 + quad*4] = o;
        }
    }
}

// ---------------- MFMA flash attention: 8-wave, key x m-half split, c-outer ----------------
// Block = (b,h, pair p), 512 threads. Wave = (key-rank kw=w&3, m-half mh=w>>2).
// Tile 31-p then p; chunks it = kw, kw+4, ... for the wave's 32 rows.
// c-OUTER body: kfc[2][2] (8 loads) + vfc[4] (4 loads) live per 32-key half.
// Pressure: o[4][2]=32acc + qf16 + kfc16 + vfc16 + temps ~115 <= 128 ->
// 4 waves/SIMD (pow2 residency quantum, R21-confirmed). exp2 in-place into
// s0/s1 via __builtin_amdgcn_exp2f. K/V L2 read 2x (XCD-local). Per-half
// combine tree (R19-proven). 512 blocks = 2/CU = 16 waves/CU.
__global__ __launch_bounds__(512, 4) void attn_mfma_kernel(
    const unsigned short* __restrict__ Qbf, const unsigned short* __restrict__ Kbf,
    const unsigned short* __restrict__ vT, unsigned short* __restrict__ Obf)
{
    // combine scratch: per half mh, 2 slots of 8 floatx4 x 64 lanes
    __shared__ __align__(16) floatx4 os[2][2][512];   // 32 KB
    __shared__ float ls[2][2][128];                   //  2 KB

    const int t = threadIdx.x;
    const int w = t >> 6, l = t & 63;
    const int kw = w & 3, mh = w >> 2;     // key-rank, m-half
    const int quad = l >> 4, col = l & 15;

    // decode: xcd = lin&7; j = lin>>3 in [0,64): rem = j&3 -> (b, h-half),
    // p = j>>2 in [0,16) -> tile pair (31-p, p). h = (lin&7) + 8*(rem>>1).
    const int lin = blockIdx.x;
    const int jj  = lin >> 3, rem = jj & 3;
    const int p   = jj >> 2;
    const int b   = rem & 1;
    const int h   = (lin & 7) + 8 * (rem >> 1);

    const size_t hoff = (size_t)h * HD;
    const size_t bS   = (size_t)b * SDIM;
    const size_t bD   = (size_t)b * DDIM;

    // per-lane permuted K-row within a 32-key pair: (col>>2)*8 + (col&3)
    const int rowp = ((col >> 2) << 3) | (col & 3);
    const unsigned short* kb0 = Kbf + bS * DDIM + hoff + quad*8;
    const unsigned short* vb0 = vT + (bD + hoff + col) * SDIM + quad*8;

    #pragma unroll 1
    for (int ph = 0; ph < 2; ++ph) {
        const int qT = ph ? p : (31 - p);
        const int qb = qT * 64;

        // persistent Q fragments for this wave's 32 rows (mh half):
        // B-frag  Q[qb + mh*32 + m*16 + col][hoff + hf*32 + quad*8 + j]
        short8 qf[2][2];
        #pragma unroll
        for (int m = 0; m < 2; ++m)
            #pragma unroll
            for (int hf = 0; hf < 2; ++hf)
                qf[m][hf] = *(const short8*)
                    &Qbf[(bS + qb + mh*32 + m*16 + col) * DDIM
                         + hoff + hf*32 + quad*8];

        floatx4 o[4][2] = {};          // o[n][m]: O^T tile (hd n, qrow m)
        float lrun[2] = {0.f, 0.f};

        #pragma unroll 1
        for (int it = kw; it <= qT; it += 4) {
            const int ktb = it * 64;
            const bool diag = (it == qT);

            #pragma unroll
            for (int c = 0; c < 2; ++c) {
                // skip half-chunk fully above the diagonal for both m rows
                if (diag && (c*32 > mh*32 + 31)) continue;

                // K fragments for this 32-key half (16 VGPR live):
                // A[row -> key ktb+c*32+perm][hd hf*32+quad*8+j]
                short8 kfc[2][2];
                #pragma unroll
                for (int tt = 0; tt < 2; ++tt) {
                    const size_t row = (size_t)(ktb + c*32 + tt*4 + rowp);
                    kfc[tt][0] = *(const short8*)&kb0[row * DDIM];
                    kfc[tt][1] = *(const short8*)&kb0[row * DDIM + 32];
                }
                // V fragments for this half (16 VGPR live):
                // A[row=hd n*16+(l&15)][key ktb+c*32+quad*8+j]
                short8 vfc[4];
                #pragma unroll
                for (int n = 0; n < 4; ++n)
                    vfc[n] = *(const short8*)
                        &vb0[(size_t)(n*16) * SDIM + ktb + c*32];

                #pragma unroll
                for (int m = 0; m < 2; ++m) {
                    const int mrow = mh*32 + m*16;
                    if (diag && (c*32 > mrow + 15)) continue;   // fully masked
                    const bool needm = diag && (c*32 + 31 > mrow);

                    floatx4 s0 = {}, s1 = {};
                    __builtin_amdgcn_s_setprio(1);
                    s0 = __builtin_amdgcn_mfma_f32_16x16x32_bf16(kfc[0][0], qf[m][0], s0, 0, 0, 0);
                    s0 = __builtin_amdgcn_mfma_f32_16x16x32_bf16(kfc[0][1], qf[m][1], s0, 0, 0, 0);
                    s1 = __builtin_amdgcn_mfma_f32_16x16x32_bf16(kfc[1][0], qf[m][0], s1, 0, 0, 0);
                    s1 = __builtin_amdgcn_mfma_f32_16x16x32_bf16(kfc[1][1], qf[m][1], s1, 0, 0, 0);
                    __builtin_amdgcn_s_setprio(0);

                    // lane's keys: tile0 -> c*32+quad*8+r, tile1 -> +4;
                    // exp in place (raw v_exp_f32; masked lanes -> exp2(-1e30)=0)
                    const int qrow = mrow + col;
                    const int kls  = c*32 + quad*8;
                    #pragma unroll
                    for (int rr = 0; rr < 4; ++rr) {
                        float x0 = (needm && (kls + rr     > qrow)) ? -1e30f : s0[rr];
                        float x1 = (needm && (kls + 4 + rr > qrow)) ? -1e30f : s1[rr];
                        s0[rr] = __builtin_amdgcn_exp2f(x0);
                        s1[rr] = __builtin_amdgcn_exp2f(x1);
                    }
                    lrun[m] += ((s0[0]+s0[1]) + (s0[2]+s0[3]))
                             + ((s1[0]+s1[1]) + (s1[2]+s1[3]));

                    union { short8 v; unsigned int u[4]; } pf;
                    pf.u[0] = pack2bf(s0[0], s0[1]);
                    pf.u[1] = pack2bf(s0[2], s0[3]);
                    pf.u[2] = pack2bf(s1[0], s1[1]);
                    pf.u[3] = pack2bf(s1[2], s1[3]);

                    __builtin_amdgcn_s_setprio(1);
                    #pragma unroll
                    for (int n = 0; n < 4; ++n)
                        o[n][m] = __builtin_amdgcn_mfma_f32_16x16x32_bf16(
                            vfc[n], pf.v, o[n][m], 0, 0, 0);
                    __builtin_amdgcn_s_setprio(0);
                }
            }
        }

        // ---- per-half combine: ranks (0+2),(1+3) -> (0+1), rank 0 stores ----
        if (kw >= 2) {
            const int s = kw - 2;
            #pragma unroll
            for (int n = 0; n < 4; ++n)
                #pragma unroll
                for (int m = 0; m < 2; ++m)
                    os[mh][s][(n*2 + m)*64 + l] = o[n][m];
            #pragma unroll
            for (int m = 0; m < 2; ++m)
                ls[mh][s][m*64 + l] = lrun[m];
        }
        __syncthreads();
        if (kw < 2) {
            #pragma unroll
            for (int n = 0; n < 4; ++n)
                #pragma unroll
                for (int m = 0; m < 2; ++m)
                    o[n][m] += os[mh][kw][(n*2 + m)*64 + l];
            #pragma unroll
            for (int m = 0; m < 2; ++m)
                lrun[m] += ls[mh][kw][m*64 + l];
        }
        __syncthreads();
        if (kw == 1) {
            #pragma unroll
            for (int n = 0; n < 4; ++n)
                #pragma unroll
                for (int m = 0; m < 2; ++m)
                    os[mh][0][(n*2 + m)*64 + l] = o[n][m];
            #pragma unroll
            for (int m = 0; m < 2; ++m)
                ls[mh][0][m*64 + l] = lrun[m];
        }
        __syncthreads();
        if (kw == 0) {
            #pragma unroll
            for (int m = 0; m < 2; ++m) {
                float lt = lrun[m] + ls[mh][0][m*64 + l];
                lt += __shfl_xor(lt, 16);
                lt += __shfl_xor(lt, 32);
                const float inv = 1.0f / lt;
                #pragma unroll
                for (int n = 0; n < 4; ++n) {
                    const floatx4 ov = o[n][m] + os[mh][0][(n*2 + m)*64 + l];
                    uint2 pk;
                    pk.x = pack2bf(ov[0] * inv, ov[1] * inv);
                    pk.y = pack2bf(ov[2] * inv, ov[3] * inv);
                    *(uint2*)&Obf[(bS + qb + mh*32 + m*16 + col) * DDIM
                                  + hoff + n*16 + quad*4] = pk;
                }
            }
        }
        __syncthreads();   // LDS reused by next phase
    }
}

extern "C" void kernel_launch(void* const* d_in, const int* in_sizes, int n_in,
                              void* d_out, int out_size, void* d_ws, size_t ws_size,
                              hipStream_t stream) {
    const float* x  = (const float*)d_in[0];
    const float* y  = (const float*)d_in[1];
    const float* Wq = (const float*)d_in[2];
    const float* bq = (const float*)d_in[3];
    const float* Wk = (const float*)d_in[4];
    const float* bk = (const float*)d_in[5];
    const float* Wv = (const float*)d_in[6];
    const float* bv = (const float*)d_in[7];
    const float* Wo = (const float*)d_in[8];
    const float* bo = (const float*)d_in[9];
    float* out = (float*)d_out;

    const size_t mat  = (size_t)MDIM * DDIM;
    const size_t wmat = (size_t)DDIM * DDIM;
    unsigned short* p = (unsigned short*)d_ws;
    unsigned short* xbf = p;            p += mat;
    unsigned short* ybf = p;            p += mat;
    unsigned short* Wqt = p;            p += wmat;
    unsigned short* Wkt = p;            p += wmat;
    unsigned short* Wvt = p;            p += wmat;
    unsigned short* Wot = p;            p += wmat;
    unsigned short* Qbf = p;            p += mat;
    unsigned short* Kbf = p;            p += mat;
    unsigned short* vT  = p;            p += mat;
    unsigned short* Obf = p;            p += mat;

    hipLaunchKernelGGL(prep_kernel, dim3(MDIM*DDIM/8/256, 1, 3), dim3(256),
                       0, stream, x, y, Wq, Wk, Wv, Wo,
                       xbf, ybf, Wqt, Wkt, Wvt, Wot);

    hipLaunchKernelGGL(qkv_gemm_kernel, dim3(DDIM/128, MDIM/128, 3), dim3(256),
                       0, stream, xbf, ybf, Wqt, Wkt, Wvt, bq, bk, bv,
                       Qbf, Kbf, vT);

    hipLaunchKernelGGL(attn_mfma_kernel, dim3(512), dim3(512),
                       0, stream, Qbf, Kbf, vT, Obf);

    hipLaunchKernelGGL(out_gemm_kernel, dim3(DDIM/64, MDIM/128), dim3(256),
                       0, stream, Obf, Wot, bo, out);
}

// Round 13
// 205.292 us; speedup vs baseline: 1.1232x; 1.1232x over previous
//
#include <hip/hip_runtime.h>
#include <hip/hip_bf16.h>

// CrossAttention  B=2, S=2048, D=1024, H=16, HD=64
// R23: occupancy ladder closed (R22: 4-wave class => VGPR squeezed to 64,
// spill, 74us; 2 waves/SIMD at ~50us is this decomposition's ceiling).
// R18 retro-proved memory latency ~0 => the 50us is VALU + dependency
// bubbles. R23 = R21 verbatim except three inner-loop cuts:
//  1) remove all s_setprio brackets (32/chunk) -> scheduler may interleave
//     independent (m,c) chains (m190: setprio HURT GEMM-like loops);
//  2) wave-uniform branch for the causal mask (cndmask only on the diagonal
//     chunk, 1 of ~8, instead of every iteration);
//  3) raw __builtin_amdgcn_exp2f (1 inst) instead of ocml exp2f (~5) --
//     correctness validated by R22 (absmax unchanged).
// No structural, register, or sync changes. prep/qkv/out unchanged.

#define BDIM 2
#define SDIM 2048
#define DDIM 1024
#define HDIM 16
#define HD   64
#define MDIM (BDIM*SDIM)   // 4096
// folded into Q at projection: (1/8) * log2(e)
#define C2 0.18033688011112042f

using short8  = __attribute__((ext_vector_type(8))) short;
using floatx4 = __attribute__((ext_vector_type(4))) float;

static __device__ __forceinline__ unsigned short f2bf(float x) {
    union { float f; unsigned int u; } c; c.f = x;
    unsigned int r = (c.u + 0x7fffu + ((c.u >> 16) & 1u)) >> 16;
    return (unsigned short)r;
}

// pack two fp32 -> (bf16(b)<<16)|bf16(a), round-half-up
static __device__ __forceinline__ unsigned int pack2bf(float a, float b) {
    union { float f; unsigned int u; } ua, ub;
    ua.f = a; ub.f = b;
    return __builtin_amdgcn_perm(ub.u + 0x8000u, ua.u + 0x8000u, 0x07060302u);
}

#define GLD16(g, l) __builtin_amdgcn_global_load_lds(                        \
    (const __attribute__((address_space(1))) void*)(g),                      \
    (__attribute__((address_space(3))) void*)(l), 16, 0, 0)

// ---------------- fused prep: cast x/y -> bf16 (z=0,1), wtrans (z=2) ----------------
__global__ __launch_bounds__(256) void prep_kernel(
    const float* __restrict__ X, const float* __restrict__ Y,
    const float* __restrict__ W0, const float* __restrict__ W1,
    const float* __restrict__ W2, const float* __restrict__ W3,
    unsigned short* __restrict__ Xo, unsigned short* __restrict__ Yo,
    unsigned short* __restrict__ T0, unsigned short* __restrict__ T1,
    unsigned short* __restrict__ T2, unsigned short* __restrict__ T3)
{
    __shared__ float tile[64][68];
    const int z = blockIdx.z;
    const int t = threadIdx.x;
    if (z < 2) {
        const float* A    = z ? Y : X;
        unsigned short* O = z ? Yo : Xo;
        const int idx = blockIdx.x * 256 + t;
        const float4 a = ((const float4*)A)[idx*2];
        const float4 b = ((const float4*)A)[idx*2 + 1];
        ushort4 lo, hi;
        lo.x = f2bf(a.x); lo.y = f2bf(a.y); lo.z = f2bf(a.z); lo.w = f2bf(a.w);
        hi.x = f2bf(b.x); hi.y = f2bf(b.y); hi.z = f2bf(b.z); hi.w = f2bf(b.w);
        ((ushort4*)O)[idx*2]     = lo;
        ((ushort4*)O)[idx*2 + 1] = hi;
        return;
    }
    // z == 2: all four weight transposes, 256 tile-blocks each
    if (blockIdx.x >= 1024) return;
    const int zz = blockIdx.x >> 8;
    const int tx = blockIdx.x & 255;
    const float* W    = (zz == 0) ? W0 : (zz == 1) ? W1 : (zz == 2) ? W2 : W3;
    unsigned short* T = (zz == 0) ? T0 : (zz == 1) ? T1 : (zz == 2) ? T2 : T3;
    const int k0 = (tx & 15) * 64, n0 = (tx >> 4) * 64;
    #pragma unroll
    for (int i = 0; i < 4; ++i) {
        const int idx = t + i*256;
        const int kr = idx >> 4, c4 = idx & 15;
        float4 v = *(const float4*)&W[(size_t)(k0 + kr) * DDIM + n0 + c4*4];
        tile[kr][c4*4+0] = v.x; tile[kr][c4*4+1] = v.y;
        tile[kr][c4*4+2] = v.z; tile[kr][c4*4+3] = v.w;
    }
    __syncthreads();
    #pragma unroll
    for (int i = 0; i < 4; ++i) {
        const int idx = t + i*256;
        const int nr = idx >> 4, kc = idx & 15;
        ushort4 o;
        o.x = f2bf(tile[kc*4+0][nr]); o.y = f2bf(tile[kc*4+1][nr]);
        o.z = f2bf(tile[kc*4+2][nr]); o.w = f2bf(tile[kc*4+3][nr]);
        *(ushort4*)&T[(size_t)(n0 + nr) * DDIM + k0 + kc*4] = o;
    }
}

// ---------------- 128x128 bf16 MFMA GEMM core, LDS double-buffered ----------------
template <bool SWAP>
__device__ __forceinline__ void gemm128_core(
    const unsigned short* __restrict__ A, const unsigned short* __restrict__ Bt,
    int bm, int bn, unsigned short* As, unsigned short* Bs, floatx4 acc[4][4])
{
    const int t = threadIdx.x;
    const int w = t >> 6, l = t & 63;
    const int quad = l >> 4, col = l & 15;
    const int wr = (w >> 1) * 64, wc = (w & 1) * 64;

    const int c1 = t + 256;
    const int r0 = t >> 2,  o0 = (t & 3) * 8;
    const int r1 = c1 >> 2, o1 = (c1 & 3) * 8;

    const unsigned short* Ar0 = A  + (size_t)(bm + r0) * DDIM + o0;
    const unsigned short* Ar1 = A  + (size_t)(bm + r1) * DDIM + o1;
    const unsigned short* Br0 = Bt + (size_t)(bn + r0) * DDIM + o0;
    const unsigned short* Br1 = Bt + (size_t)(bn + r1) * DDIM + o1;

    GLD16(Ar0, As + t*8);
    GLD16(Ar1, As + c1*8);
    GLD16(Br0, Bs + t*8);
    GLD16(Br1, Bs + c1*8);

    for (int kt = 0; kt < DDIM; kt += 32) {
        const int cur = (kt >> 5) & 1;
        unsigned short* Asn = As + (cur ^ 1) * 4096;
        unsigned short* Bsn = Bs + (cur ^ 1) * 4096;
        __syncthreads();
        if (kt + 32 < DDIM) {
            GLD16(Ar0 + kt + 32, Asn + t*8);
            GLD16(Ar1 + kt + 32, Asn + c1*8);
            GLD16(Br0 + kt + 32, Bsn + t*8);
            GLD16(Br1 + kt + 32, Bsn + c1*8);
        }
        const unsigned short* Asc = As + cur*4096;
        const unsigned short* Bsc = Bs + cur*4096;
        short8 af[4], bfr[4];
        #pragma unroll
        for (int i = 0; i < 4; ++i)
            af[i] = *(const short8*)&Asc[(wr + i*16 + col)*32 + quad*8];
        #pragma unroll
        for (int j = 0; j < 4; ++j)
            bfr[j] = *(const short8*)&Bsc[(wc + j*16 + col)*32 + quad*8];
        #pragma unroll
        for (int i = 0; i < 4; ++i)
            #pragma unroll
            for (int j = 0; j < 4; ++j)
                acc[i][j] = SWAP
                    ? __builtin_amdgcn_mfma_f32_16x16x32_bf16(bfr[j], af[i], acc[i][j], 0, 0, 0)
                    : __builtin_amdgcn_mfma_f32_16x16x32_bf16(af[i], bfr[j], acc[i][j], 0, 0, 0);
    }
}

// ---------------- fused Q/K/V projection (grid.z = 0/1/2) ----------------
// XCD swizzle: raw (x,y) with x in [0,8): xcd = x (lin%8). bm = x*4+(y&3),
// bn = y>>2 -> per-XCD A set = 4 tiles (1MB), W = 2MB: both L2-resident.
__global__ __launch_bounds__(256) void qkv_gemm_kernel(
    const unsigned short* __restrict__ xbf, const unsigned short* __restrict__ ybf,
    const unsigned short* __restrict__ Wqt, const unsigned short* __restrict__ Wkt,
    const unsigned short* __restrict__ Wvt,
    const float* __restrict__ bq, const float* __restrict__ bk,
    const float* __restrict__ bv,
    unsigned short* __restrict__ Qbf, unsigned short* __restrict__ Kbf,
    unsigned short* __restrict__ vT)
{
    __shared__ __align__(16) unsigned short As[2*4096];   // 16 KB
    __shared__ __align__(16) unsigned short Bs[2*4096];   // 16 KB

    const int z = blockIdx.z;
    const unsigned short* A  = (z == 0) ? xbf : ybf;
    const unsigned short* Wt = (z == 0) ? Wqt : (z == 1) ? Wkt : Wvt;
    const float* bp          = (z == 0) ? bq  : (z == 1) ? bk  : bv;

    // XCD-aware remap (grid (8,32,z)): xcd = blockIdx.x
    const int bm = (blockIdx.x * 4 + (blockIdx.y & 3)) * 128;
    const int bn = (blockIdx.y >> 2) * 128;

    const int t = threadIdx.x;
    const int w = t >> 6, l = t & 63;
    const int quad = l >> 4, col = l & 15;
    const int wr = (w >> 1) * 64, wc = (w & 1) * 64;

    floatx4 acc[4][4] = {};

    if (z < 2) {
        gemm128_core<true>(A, Wt, bm, bn, As, Bs, acc);
        unsigned short* O = (z == 0) ? Qbf : Kbf;
        const float sc = (z == 0) ? C2 : 1.0f;
        float4 bias4[4];
        #pragma unroll
        for (int j = 0; j < 4; ++j)
            bias4[j] = *(const float4*)&bp[bn + wc + j*16 + quad*4];
        #pragma unroll
        for (int i = 0; i < 4; ++i) {
            const int m = bm + wr + i*16 + col;
            unsigned short* rowp = O + (size_t)m * DDIM;
            #pragma unroll
            for (int j = 0; j < 4; ++j) {
                const float v0 = (acc[i][j][0] + bias4[j].x) * sc;
                const float v1 = (acc[i][j][1] + bias4[j].y) * sc;
                const float v2 = (acc[i][j][2] + bias4[j].z) * sc;
                const float v3 = (acc[i][j][3] + bias4[j].w) * sc;
                uint2 pk;
                pk.x = pack2bf(v0, v1);
                pk.y = pack2bf(v2, v3);
                *(uint2*)&rowp[bn + wc + j*16 + quad*4] = pk;
            }
        }
    } else {
        gemm128_core<false>(A, Wt, bm, bn, As, Bs, acc);
        #pragma unroll
        for (int j = 0; j < 4; ++j) {
            const int gn = bn + wc + j*16 + col;
            const float bias = bp[gn];
            #pragma unroll
            for (int i = 0; i < 4; ++i) {
                const int gm0 = bm + wr + i*16 + quad*4;
                uint2 pk;
                pk.x = pack2bf(acc[i][j][0] + bias, acc[i][j][1] + bias);
                pk.y = pack2bf(acc[i][j][2] + bias, acc[i][j][3] + bias);
                *(uint2*)&vT[((size_t)((gm0 >> 11) * DDIM + gn)) * SDIM + (gm0 & 2047)] = pk;
            }
        }
    }
}

// ---------------- output projection: 128x64 tiles, double-buffered ----------------
// XCD swizzle: grid (16,32); xcd = x&7, j = (x>>3) + 2y in [0,64):
// bm = (x&7)*4 + (j&3), bn = j>>2 -> per-XCD 1MB A + 2MB W, L2-resident.
__global__ __launch_bounds__(256) void out_gemm_kernel(
    const unsigned short* __restrict__ Obf, const unsigned short* __restrict__ Wot,
    const float* __restrict__ bo, float* __restrict__ out)
{
    __shared__ __align__(16) unsigned short As[2*4096];   // 16 KB
    __shared__ __align__(16) unsigned short Bs[2*2048];   // 8 KB

    const int t = threadIdx.x;
    const int w = t >> 6, l = t & 63;
    const int quad = l >> 4, col = l & 15;

    const int j  = (blockIdx.x >> 3) + 2 * blockIdx.y;
    const int bm = ((blockIdx.x & 7) * 4 + (j & 3)) * 128;
    const int bn = (j >> 2) * 64;

    const int wr = (w >> 1) * 64, wc = (w & 1) * 32;

    const int r0 = t >> 2, o0 = (t & 3) * 8;
    const unsigned short* Ar0 = Obf + (size_t)(bm + r0) * DDIM + o0;
    const unsigned short* Ar1 = Obf + (size_t)(bm + 64 + r0) * DDIM + o0;
    const unsigned short* Br  = Wot + (size_t)(bn + r0) * DDIM + o0;

    floatx4 acc[4][2] = {};

    GLD16(Ar0, As + t*8);
    GLD16(Ar1, As + (t + 256)*8);
    GLD16(Br,  Bs + t*8);

    for (int kt = 0; kt < DDIM; kt += 32) {
        const int cur = (kt >> 5) & 1;
        unsigned short* Asn = As + (cur ^ 1) * 4096;
        unsigned short* Bsn = Bs + (cur ^ 1) * 2048;
        __syncthreads();
        if (kt + 32 < DDIM) {
            GLD16(Ar0 + kt + 32, Asn + t*8);
            GLD16(Ar1 + kt + 32, Asn + (t + 256)*8);
            GLD16(Br  + kt + 32, Bsn + t*8);
        }
        const unsigned short* Asc = As + cur*4096;
        const unsigned short* Bsc = Bs + cur*2048;
        short8 af[4], bfr[2];
        #pragma unroll
        for (int i = 0; i < 4; ++i)
            af[i] = *(const short8*)&Asc[(wr + i*16 + col)*32 + quad*8];
        #pragma unroll
        for (int j2 = 0; j2 < 2; ++j2)
            bfr[j2] = *(const short8*)&Bsc[(wc + j2*16 + col)*32 + quad*8];
        #pragma unroll
        for (int i = 0; i < 4; ++i)
            #pragma unroll
            for (int j2 = 0; j2 < 2; ++j2)
                acc[i][j2] = __builtin_amdgcn_mfma_f32_16x16x32_bf16(
                    bfr[j2], af[i], acc[i][j2], 0, 0, 0);
    }

    float4 bias4[2];
    #pragma unroll
    for (int j2 = 0; j2 < 2; ++j2)
        bias4[j2] = *(const float4*)&bo[bn + wc + j2*16 + quad*4];
    #pragma unroll
    for (int i = 0; i < 4; ++i) {
        const int m = bm + wr + i*16 + col;
        float* rowp = out + (size_t)m * DDIM;
        #pragma unroll
        for (int j2 = 0; j2 < 2; ++j2) {
            float4 o;
            o.x = acc[i][j2][0] + bias4[j2].x;
            o.y = acc[i][j2][1] + bias4[j2].y;
            o.z = acc[i][j2][2] + bias4[j2].z;
            o.w = acc[i][j2][3] + bias4[j2].w;
            *(float4*)&rowp[bn + wc + j2*16 + quad*4] = o;
        }
    }
}

// ---------------- MFMA flash attention: single-tile blocks, lean inner loop ----------------
// Block = one 64-row q-tile of one (b,h); 1024 blocks (longest-first per XCD
// via qt = 31-(j>>2); dynamic refill). 4 waves split 64-key chunks
// round-robin. c-OUTER body (kfc16 + vfc16 live). No setprio (scheduler
// freedom); wave-uniform mask branch (cndmask only on diagonal chunk);
// raw v_exp_f32 via __builtin_amdgcn_exp2f. In-register P via key
// permutation. Combine: 2-slot LDS tree (34KB). launch_bounds(256,2).
__global__ __launch_bounds__(256, 2) void attn_mfma_kernel(
    const unsigned short* __restrict__ Qbf, const unsigned short* __restrict__ Kbf,
    const unsigned short* __restrict__ vT, unsigned short* __restrict__ Obf)
{
    __shared__ float ls[2][4*64];                 //  2 KB
    __shared__ __align__(16) floatx4 os[2][1024]; // 32 KB

    const int t = threadIdx.x;
    const int w = t >> 6, l = t & 63;
    const int quad = l >> 4, col = l & 15;

    // decode: lin = xcd + 8*j; j = rem + 4*(31-qt); h = xcd + 8*(rem>>1)
    const int lin = blockIdx.x;
    const int j   = lin >> 3, rem = j & 3;
    const int qT  = 31 - (j >> 2);
    const int b   = rem & 1;
    const int h   = (lin & 7) + 8 * (rem >> 1);

    const size_t hoff = (size_t)h * HD;
    const size_t bS   = (size_t)b * SDIM;
    const size_t bD   = (size_t)b * DDIM;
    const int qb = qT * 64;

    // per-lane permuted K-row within a 32-key pair: (col>>2)*8 + (col&3)
    const int rowp = ((col >> 2) << 3) | (col & 3);
    const unsigned short* kb0 = Kbf + bS * DDIM + hoff + quad*8;
    const unsigned short* vb0 = vT + (bD + hoff + col) * SDIM + quad*8;

    // persistent Q fragments: B-frag  Q[qb+m*16+col][hoff + hf*32 + quad*8 + j]
    short8 qf[4][2];
    #pragma unroll
    for (int m = 0; m < 4; ++m)
        #pragma unroll
        for (int hf = 0; hf < 2; ++hf)
            qf[m][hf] = *(const short8*)
                &Qbf[(bS + qb + m*16 + col) * DDIM + hoff + hf*32 + quad*8];

    floatx4 o[4][4] = {};          // o[n][m]: O^T tile (hd n, qrow m)
    float lrun[4] = {0.f, 0.f, 0.f, 0.f};

    #pragma unroll 1
    for (int it = w; it <= qT; it += 4) {
        const int ktb = it * 64;
        const bool diag = (it == qT);

        #pragma unroll
        for (int c = 0; c < 2; ++c) {
            // K fragments for this 32-key half (16 VGPR live):
            // A[row -> key ktb+c*32+perm][hd hf*32+quad*8+j]
            short8 kfc[2][2];
            #pragma unroll
            for (int tt = 0; tt < 2; ++tt) {
                const size_t row = (size_t)(ktb + c*32 + tt*4 + rowp);
                kfc[tt][0] = *(const short8*)&kb0[row * DDIM];
                kfc[tt][1] = *(const short8*)&kb0[row * DDIM + 32];
            }
            // V fragments for this half (16 VGPR live):
            // A[row=hd n*16+(l&15)][key ktb+c*32+quad*8+j]
            short8 vfc[4];
            #pragma unroll
            for (int n = 0; n < 4; ++n)
                vfc[n] = *(const short8*)
                    &vb0[(size_t)(n*16) * SDIM + ktb + c*32];

            #pragma unroll
            for (int m = 0; m < 4; ++m) {
                if (diag && (c*32 > m*16 + 15)) continue;   // fully masked
                const bool needm = diag && (c*32 + 31 > m*16);

                floatx4 s0 = {}, s1 = {};
                s0 = __builtin_amdgcn_mfma_f32_16x16x32_bf16(kfc[0][0], qf[m][0], s0, 0, 0, 0);
                s0 = __builtin_amdgcn_mfma_f32_16x16x32_bf16(kfc[0][1], qf[m][1], s0, 0, 0, 0);
                s1 = __builtin_amdgcn_mfma_f32_16x16x32_bf16(kfc[1][0], qf[m][0], s1, 0, 0, 0);
                s1 = __builtin_amdgcn_mfma_f32_16x16x32_bf16(kfc[1][1], qf[m][1], s1, 0, 0, 0);

                // exp2 in place; masks only on the diagonal chunk (wave-
                // uniform branch). exp2(-1e30) flushes to 0.
                if (needm) {
                    const int qrow = m*16 + col;
                    const int kls  = c*32 + quad*8;
                    #pragma unroll
                    for (int rr = 0; rr < 4; ++rr) {
                        s0[rr] = __builtin_amdgcn_exp2f(
                            (kls + rr     > qrow) ? -1e30f : s0[rr]);
                        s1[rr] = __builtin_amdgcn_exp2f(
                            (kls + 4 + rr > qrow) ? -1e30f : s1[rr]);
                    }
                } else {
                    #pragma unroll
                    for (int rr = 0; rr < 4; ++rr) {
                        s0[rr] = __builtin_amdgcn_exp2f(s0[rr]);
                        s1[rr] = __builtin_amdgcn_exp2f(s1[rr]);
                    }
                }
                lrun[m] += ((s0[0]+s0[1]) + (s0[2]+s0[3]))
                         + ((s1[0]+s1[1]) + (s1[2]+s1[3]));

                union { short8 v; unsigned int u[4]; } pf;
                pf.u[0] = pack2bf(s0[0], s0[1]);
                pf.u[1] = pack2bf(s0[2], s0[3]);
                pf.u[2] = pack2bf(s1[0], s1[1]);
                pf.u[3] = pack2bf(s1[2], s1[3]);

                #pragma unroll
                for (int n = 0; n < 4; ++n)
                    o[n][m] = __builtin_amdgcn_mfma_f32_16x16x32_bf16(
                        vfc[n], pf.v, o[n][m], 0, 0, 0);
            }
        }
    }

    // ---- cross-wave combine: (0+2), (1+3), then (0+1), wave 0 stores ----
    if (w >= 2) {
        const int s = w - 2;
        #pragma unroll
        for (int n = 0; n < 4; ++n)
            #pragma unroll
            for (int m = 0; m < 4; ++m)
                os[s][(n*4 + m)*64 + l] = o[n][m];
        #pragma unroll
        for (int m = 0; m < 4; ++m)
            ls[s][m*64 + l] = lrun[m];
    }
    __syncthreads();
    if (w < 2) {
        #pragma unroll
        for (int n = 0; n < 4; ++n)
            #pragma unroll
            for (int m = 0; m < 4; ++m)
                o[n][m] += os[w][(n*4 + m)*64 + l];
        #pragma unroll
        for (int m = 0; m < 4; ++m)
            lrun[m] += ls[w][m*64 + l];
    }
    __syncthreads();
    if (w == 1) {
        #pragma unroll
        for (int n = 0; n < 4; ++n)
            #pragma unroll
            for (int m = 0; m < 4; ++m)
                os[0][(n*4 + m)*64 + l] = o[n][m];
        #pragma unroll
        for (int m = 0; m < 4; ++m)
            ls[0][m*64 + l] = lrun[m];
    }
    __syncthreads();
    if (w == 0) {
        #pragma unroll
        for (int m = 0; m < 4; ++m) {
            float lt = lrun[m] + ls[0][m*64 + l];
            lt += __shfl_xor(lt, 16);
            lt += __shfl_xor(lt, 32);
            const float inv = 1.0f / lt;
            #pragma unroll
            for (int n = 0; n < 4; ++n) {
                const floatx4 ov = o[n][m] + os[0][(n*4 + m)*64 + l];
                uint2 pk;
                pk.x = pack2bf(ov[0] * inv, ov[1] * inv);
                pk.y = pack2bf(ov[2] * inv, ov[3] * inv);
                *(uint2*)&Obf[(bS + qb + m*16 + col) * DDIM
                              + hoff + n*16 + quad*4] = pk;
            }
        }
    }
}

extern "C" void kernel_launch(void* const* d_in, const int* in_sizes, int n_in,
                              void* d_out, int out_size, void* d_ws, size_t ws_size,
                              hipStream_t stream) {
    const float* x  = (const float*)d_in[0];
    const float* y  = (const float*)d_in[1];
    const float* Wq = (const float*)d_in[2];
    const float* bq = (const float*)d_in[3];
    const float* Wk = (const float*)d_in[4];
    const float* bk = (const float*)d_in[5];
    const float* Wv = (const float*)d_in[6];
    const float* bv = (const float*)d_in[7];
    const float* Wo = (const float*)d_in[8];
    const float* bo = (const float*)d_in[9];
    float* out = (float*)d_out;

    const size_t mat  = (size_t)MDIM * DDIM;
    const size_t wmat = (size_t)DDIM * DDIM;
    unsigned short* p = (unsigned short*)d_ws;
    unsigned short* xbf = p;            p += mat;
    unsigned short* ybf = p;            p += mat;
    unsigned short* Wqt = p;            p += wmat;
    unsigned short* Wkt = p;            p += wmat;
    unsigned short* Wvt = p;            p += wmat;
    unsigned short* Wot = p;            p += wmat;
    unsigned short* Qbf = p;            p += mat;
    unsigned short* Kbf = p;            p += mat;
    unsigned short* vT  = p;            p += mat;
    unsigned short* Obf = p;            p += mat;

    hipLaunchKernelGGL(prep_kernel, dim3(MDIM*DDIM/8/256, 1, 3), dim3(256),
                       0, stream, x, y, Wq, Wk, Wv, Wo,
                       xbf, ybf, Wqt, Wkt, Wvt, Wot);

    hipLaunchKernelGGL(qkv_gemm_kernel, dim3(DDIM/128, MDIM/128, 3), dim3(256),
                       0, stream, xbf, ybf, Wqt, Wkt, Wvt, bq, bk, bv,
                       Qbf, Kbf, vT);

    hipLaunchKernelGGL(attn_mfma_kernel, dim3(1024), dim3(256),
                       0, stream, Qbf, Kbf, vT, Obf);

    hipLaunchKernelGGL(out_gemm_kernel, dim3(DDIM/64, MDIM/128), dim3(256),
                       0, stream, Obf, Wot, bo, out);
}